// Round 7
// baseline (450.177 us; speedup 1.0000x reference)
//
#include <hip/hip_runtime.h>
#include <hip/hip_bf16.h>

// B=1024, S=128, E=256, H=2, DH=128.  v/Wv/bv are dead in the reference.
// out = softmax( (q@Wq+bq)/16 |head h  .  (k@Wk+bk)|head h  + (mask==0) ) @ Wo + bo
//
// Single fused kernel, 64KB LDS time-shared (KT until GEMM2 done, then P),
// 2 blocks/CU. qpT lives in registers (MFMA D-frag rows chain into B-frag
// k-slots 0..3 of the K=32 MFMA, upper 4 k-slots zeroed on both operands).
// R7: GEMM2 split over s-tiles + GEMM3 transposed (float4 out stores) to
// keep peak live regs < 128 (R6 spilled ~200MB of scratch traffic).
#define NB 1024
#define NS 128
#define NE 256

typedef __attribute__((ext_vector_type(8))) short bf16x8;
typedef __attribute__((ext_vector_type(4))) float f32x4;

union BF8 { bf16x8 v; unsigned u[4]; unsigned short s[8]; };

__device__ __forceinline__ unsigned short f2bf(float x) {
  unsigned u = __float_as_uint(x);
  u = (u + 0x7fffu + ((u >> 16) & 1u)) >> 16;   // RNE
  return (unsigned short)u;
}

__device__ __forceinline__ unsigned packbf(float lo, float hi) {
  return (unsigned)f2bf(lo) | ((unsigned)f2bf(hi) << 16);
}

__device__ __forceinline__ bf16x8 cvt8(float4 lo, float4 hi) {
  BF8 r;
  r.u[0] = packbf(lo.x, lo.y);
  r.u[1] = packbf(lo.z, lo.w);
  r.u[2] = packbf(hi.x, hi.y);
  r.u[3] = packbf(hi.z, hi.w);
  return r.v;
}

__device__ __forceinline__ f32x4 MF(bf16x8 a, bf16x8 b, f32x4 c) {
  return __builtin_amdgcn_mfma_f32_16x16x32_bf16(a, b, c, 0, 0, 0);
}

// WT[n][k] = W[k][n] bf16; Wq additionally prescaled by 1/16.
__global__ void prep_weights(const float* __restrict__ Wq,
                             const float* __restrict__ Wk,
                             const float* __restrict__ Wo,
                             short* __restrict__ WqT,
                             short* __restrict__ WkT,
                             short* __restrict__ WoT) {
  int idx = blockIdx.x * blockDim.x + threadIdx.x;  // = n*256 + k
  int n = idx >> 8;
  int kk = idx & 255;
  WqT[idx] = (short)f2bf(Wq[kk * NE + n] * 0.0625f);
  WkT[idx] = (short)f2bf(Wk[kk * NE + n]);
  WoT[idx] = (short)f2bf(Wo[kk * NE + n]);
}

// acc[et][ct] += outT tile:
//   outT[e = h*128 + et*16 + c4*4+r][col = sb*32 + ct*16 + cl]
//     = sum_c WT[e][c] * inp[col][c]
// A = WT rows (global bf16, L2-hot), B = inp rows (global f32 -> bf16).
__device__ __forceinline__ void gemm_halfT(const short* __restrict__ WT,
                                           const float* __restrict__ inp,
                                           int h, int sb, int cl, int c4,
                                           f32x4 acc[8][2]) {
  #pragma unroll
  for (int ks = 0; ks < 8; ++ks) {
    bf16x8 bb[2];
    #pragma unroll
    for (int ct = 0; ct < 2; ++ct) {
      const float* rp = inp + (sb * 32 + ct * 16 + cl) * NE + ks * 32 + c4 * 8;
      bb[ct] = cvt8(*reinterpret_cast<const float4*>(rp),
                    *reinterpret_cast<const float4*>(rp + 4));
    }
    #pragma unroll
    for (int eh = 0; eh < 2; ++eh) {
      bf16x8 a[4];
      #pragma unroll
      for (int e4 = 0; e4 < 4; ++e4) {
        int et = eh * 4 + e4;
        a[e4] = *reinterpret_cast<const bf16x8*>(
            WT + (h * 128 + et * 16 + cl) * NE + ks * 32 + c4 * 8);
      }
      #pragma unroll
      for (int e4 = 0; e4 < 4; ++e4)
        #pragma unroll
        for (int ct = 0; ct < 2; ++ct)
          acc[eh * 4 + e4][ct] = MF(a[e4], bb[ct], acc[eh * 4 + e4][ct]);
    }
  }
}

__global__ __launch_bounds__(512, 4)
void fused_attn3(const float* __restrict__ q,
                 const float* __restrict__ kin,
                 const int* __restrict__ am,
                 const short* __restrict__ WqT,
                 const short* __restrict__ WkT,
                 const short* __restrict__ WoT,
                 const float* __restrict__ bq,
                 const float* __restrict__ bk,
                 const float* __restrict__ bo,
                 float* __restrict__ out) {
  // 64KB, time-shared: KT[e][m] (256 rows x 256B, swizzled) until GEMM2 done,
  // then P[s][j] (128 rows x 512B, swizzled) for GEMM3.
  __shared__ char LB[65536];
  const int t = threadIdx.x;
  const int lane = t & 63;
  const int wid = t >> 6;        // 8 waves
  const int cl = lane & 15;
  const int c4 = lane >> 4;
  const int h = wid >> 2;        // head / e-half (0..1)
  const int sb = wid & 3;        // s-band & m-band (0..3, 32 wide)
  const int b = blockIdx.x;
  const float* qb = q + (size_t)b * (NS * NE);
  const float* kb = kin + (size_t)b * (NS * NE);

  // ---- GEMM1a: KT = (k @ Wk + bk)^T  (e-half h rows, m-band sb cols) ----
  {
    f32x4 acc[8][2];
    #pragma unroll
    for (int et = 0; et < 8; ++et)
      #pragma unroll
      for (int ct = 0; ct < 2; ++ct) acc[et][ct] = (f32x4){0.f, 0.f, 0.f, 0.f};
    gemm_halfT(WkT, kb, h, sb, cl, c4, acc);
    #pragma unroll
    for (int et = 0; et < 8; ++et) {
      int e0 = h * 128 + et * 16 + c4 * 4;       // 4 consecutive e (rows)
      float4 bk4 = *reinterpret_cast<const float4*>(bk + e0);
      #pragma unroll
      for (int mt = 0; mt < 2; ++mt) {
        int m = sb * 32 + mt * 16 + cl;
        #pragma unroll
        for (int r = 0; r < 4; ++r) {
          int e = e0 + r;
          float bv = (r == 0) ? bk4.x : (r == 1) ? bk4.y : (r == 2) ? bk4.z : bk4.w;
          *reinterpret_cast<unsigned short*>(
              LB + e * 256 + ((m * 2) ^ ((e & 7) << 4))) =
              f2bf(acc[et][mt][r] + bv);
        }
      }
    }
  }

  // ---- GEMM1b: qpT in registers (e-half h, s-band sb), packed to bf16 ----
  // qpk[et][st][p]: qpT rows (in tile et) c4*4 + {2p,2p+1}, col = st*16+cl.
  unsigned qpk[8][2][2];
  {
    f32x4 acc[8][2];
    #pragma unroll
    for (int et = 0; et < 8; ++et)
      #pragma unroll
      for (int ct = 0; ct < 2; ++ct) acc[et][ct] = (f32x4){0.f, 0.f, 0.f, 0.f};
    gemm_halfT(WqT, qb, h, sb, cl, c4, acc);   // WqT prescaled by 1/16
    #pragma unroll
    for (int et = 0; et < 8; ++et) {
      int e0 = h * 128 + et * 16 + c4 * 4;
      float4 bq4 = *reinterpret_cast<const float4*>(bq + e0);
      #pragma unroll
      for (int st = 0; st < 2; ++st) {
        qpk[et][st][0] = packbf(acc[et][st][0] + bq4.x * 0.0625f,
                                acc[et][st][1] + bq4.y * 0.0625f);
        qpk[et][st][1] = packbf(acc[et][st][2] + bq4.z * 0.0625f,
                                acc[et][st][3] + bq4.w * 0.0625f);
      }
    }
  }
  __syncthreads();   // KT fully written (all waves) before score reads

  // ---- GEMM2 (split over st to halve live regs):
  // scoresT[j][s] = sum_m KT[h*128+j][m] * qpT[h*128+m][s], K=16 chain on the
  // K=32 MFMA (k-slots {c4*8..+3} carry m = ks*16+c4*4+{0..3}; upper 4 zeroed).
  unsigned prpk[2][8][2];   // packed probs, [st][jt][pair]
  #pragma unroll
  for (int st = 0; st < 2; ++st) {
    f32x4 sacc[8];
    #pragma unroll
    for (int jt = 0; jt < 8; ++jt) sacc[jt] = (f32x4){0.f, 0.f, 0.f, 0.f};
    #pragma unroll
    for (int ks = 0; ks < 8; ++ks) {
      BF8 bb;
      bb.u[0] = qpk[ks][st][0]; bb.u[1] = qpk[ks][st][1];
      bb.u[2] = 0; bb.u[3] = 0;
      #pragma unroll
      for (int jh = 0; jh < 2; ++jh) {
        BF8 a[4];
        #pragma unroll
        for (int j4 = 0; j4 < 4; ++j4) {
          int jt = jh * 4 + j4;
          uint2 d = *reinterpret_cast<const uint2*>(
              LB + (h * 128 + jt * 16 + cl) * 256 +
              ((ks * 32 + c4 * 8) ^ ((cl & 7) << 4)));
          a[j4].u[0] = d.x; a[j4].u[1] = d.y; a[j4].u[2] = 0; a[j4].u[3] = 0;
        }
        #pragma unroll
        for (int j4 = 0; j4 < 4; ++j4)
          sacc[jh * 4 + j4] = MF(a[j4].v, bb.v, sacc[jh * 4 + j4]);
      }
    }
    // fold additive mask: +1.0 where attention_mask[b][j]==0  (j-axis!)
    #pragma unroll
    for (int jt = 0; jt < 8; ++jt) {
      int4 mv = *reinterpret_cast<const int4*>(am + b * NS + jt * 16 + c4 * 4);
      sacc[jt][0] += (mv.x == 0) ? 1.f : 0.f;
      sacc[jt][1] += (mv.y == 0) ? 1.f : 0.f;
      sacc[jt][2] += (mv.z == 0) ? 1.f : 0.f;
      sacc[jt][3] += (mv.w == 0) ? 1.f : 0.f;
    }
    // softmax along j: 32 in-lane values, then xor 16/32 across c4 groups
    float mx = -1e30f;
    #pragma unroll
    for (int jt = 0; jt < 8; ++jt)
      #pragma unroll
      for (int r = 0; r < 4; ++r) mx = fmaxf(mx, sacc[jt][r]);
    mx = fmaxf(mx, __shfl_xor(mx, 16, 64));
    mx = fmaxf(mx, __shfl_xor(mx, 32, 64));
    float sum = 0.f;
    #pragma unroll
    for (int jt = 0; jt < 8; ++jt)
      #pragma unroll
      for (int r = 0; r < 4; ++r) {
        float ev = __expf(sacc[jt][r] - mx);
        sacc[jt][r] = ev;
        sum += ev;
      }
    sum += __shfl_xor(sum, 16, 64);
    sum += __shfl_xor(sum, 32, 64);
    float rinv = 1.0f / sum;
    #pragma unroll
    for (int jt = 0; jt < 8; ++jt) {
      prpk[st][jt][0] = packbf(sacc[jt][0] * rinv, sacc[jt][1] * rinv);
      prpk[st][jt][1] = packbf(sacc[jt][2] * rinv, sacc[jt][3] * rinv);
    }
  }
  __syncthreads();   // all KT reads complete before P overwrites the region

  // ---- P[s][j] = probs bf16 (128 rows x 512B, swizzled) ----
  #pragma unroll
  for (int st = 0; st < 2; ++st) {
    int s = sb * 32 + st * 16 + cl;
    #pragma unroll
    for (int jt = 0; jt < 8; ++jt) {
      int j = h * 128 + jt * 16 + c4 * 4;
      *reinterpret_cast<uint2*>(
          LB + s * 512 + ((j * 2) ^ ((s & 7) << 4))) =
          make_uint2(prpk[st][jt][0], prpk[st][jt][1]);
    }
  }
  __syncthreads();

  // ---- GEMM3 (transposed): out[s][e] = sum_j Wo[j][e] * P[s][j] + bo[e]
  // A = WoT rows e (global, L2-hot), B = P rows s (LDS).  D rows = e -> the
  // 4 acc elems are 4 consecutive e => float4 stores.
  float* ob = out + (size_t)b * (NS * NE);
  #pragma unroll
  for (int eti = 0; eti < 2; ++eti) {
    const int et = wid * 2 + eti;               // 16 e-tiles over 8 waves
    bf16x8 a[8];
    #pragma unroll
    for (int ks = 0; ks < 8; ++ks)
      a[ks] = *reinterpret_cast<const bf16x8*>(
          WoT + (et * 16 + cl) * NE + ks * 32 + c4 * 8);
    float4 bo4 = *reinterpret_cast<const float4*>(bo + et * 16 + c4 * 4);
    #pragma unroll
    for (int su = 0; su < 8; ++su) {
      f32x4 acc = (f32x4){0.f, 0.f, 0.f, 0.f};
      const int row = su * 16 + cl;
      #pragma unroll
      for (int ks = 0; ks < 8; ++ks) {
        bf16x8 bv = *reinterpret_cast<const bf16x8*>(
            LB + row * 512 + ((ks * 64 + c4 * 16) ^ ((row & 7) << 4)));
        acc = MF(a[ks], bv, acc);
      }
      float4 o;
      o.x = acc[0] + bo4.x;
      o.y = acc[1] + bo4.y;
      o.z = acc[2] + bo4.z;
      o.w = acc[3] + bo4.w;
      *reinterpret_cast<float4*>(ob + row * NE + et * 16 + c4 * 4) = o;
    }
  }
}

extern "C" void kernel_launch(void* const* d_in, const int* in_sizes, int n_in,
                              void* d_out, int out_size, void* d_ws, size_t ws_size,
                              hipStream_t stream) {
  const float* q  = (const float*)d_in[0];
  const float* k  = (const float*)d_in[1];
  // d_in[2] = v : dead in the reference, never touched
  const int*   am = (const int*)d_in[3];
  const float* Wq = (const float*)d_in[4];
  const float* bq = (const float*)d_in[5];
  const float* Wk = (const float*)d_in[6];
  const float* bk = (const float*)d_in[7];
  // d_in[8] = Wv, d_in[9] = bv : dead
  const float* Wo = (const float*)d_in[10];
  const float* bo = (const float*)d_in[11];
  float* out = (float*)d_out;

  // workspace: 3 x 256x256 bf16 transposed weights = 384KB
  short* WqT = (short*)d_ws;
  short* WkT = WqT + NE * NE;
  short* WoT = WkT + NE * NE;

  prep_weights<<<NE * NE / 256, 256, 0, stream>>>(Wq, Wk, Wo, WqT, WkT, WoT);
  fused_attn3<<<NB, 512, 0, stream>>>(q, k, am, WqT, WkT, WoT, bq, bk, bo, out);
}

// Round 8
// 262.075 us; speedup vs baseline: 1.7177x; 1.7177x over previous
//
#include <hip/hip_runtime.h>
#include <hip/hip_bf16.h>

// B=1024, S=128, E=256, H=2, DH=128.  v/Wv/bv are dead in the reference.
// out = softmax( (q@Wq+bq)/16 |head h  .  (k@Wk+bk)|head h  + (mask==0) ) @ Wo + bo
//
// Single fused kernel, 64KB LDS time-shared (KT until GEMM2 done, then P).
// qpT lives in registers (MFMA D-frag rows chain into B-frag k-slots 0..3 of
// the K=32 MFMA, upper 4 k-slots zeroed on both operands).
// R8: __launch_bounds__(512,2). Empirically (R2 vs R6/R7) the 2nd arg=4
// imposed a 64-VGPR cap -> massive scratch spills (WRITE 646MB vs 131MB
// real). (512,2) gave VGPR=100, no spills, in R2. LDS=64KB still permits
// 2 blocks/CU at 128 VGPR (16 waves/CU = 4/SIMD).
#define NB 1024
#define NS 128
#define NE 256

typedef __attribute__((ext_vector_type(8))) short bf16x8;
typedef __attribute__((ext_vector_type(4))) float f32x4;

union BF8 { bf16x8 v; unsigned u[4]; unsigned short s[8]; };

__device__ __forceinline__ unsigned short f2bf(float x) {
  unsigned u = __float_as_uint(x);
  u = (u + 0x7fffu + ((u >> 16) & 1u)) >> 16;   // RNE
  return (unsigned short)u;
}

__device__ __forceinline__ unsigned packbf(float lo, float hi) {
  return (unsigned)f2bf(lo) | ((unsigned)f2bf(hi) << 16);
}

__device__ __forceinline__ bf16x8 cvt8(float4 lo, float4 hi) {
  BF8 r;
  r.u[0] = packbf(lo.x, lo.y);
  r.u[1] = packbf(lo.z, lo.w);
  r.u[2] = packbf(hi.x, hi.y);
  r.u[3] = packbf(hi.z, hi.w);
  return r.v;
}

__device__ __forceinline__ f32x4 MF(bf16x8 a, bf16x8 b, f32x4 c) {
  return __builtin_amdgcn_mfma_f32_16x16x32_bf16(a, b, c, 0, 0, 0);
}

// WT[n][k] = W[k][n] bf16; Wq additionally prescaled by 1/16.
__global__ void prep_weights(const float* __restrict__ Wq,
                             const float* __restrict__ Wk,
                             const float* __restrict__ Wo,
                             short* __restrict__ WqT,
                             short* __restrict__ WkT,
                             short* __restrict__ WoT) {
  int idx = blockIdx.x * blockDim.x + threadIdx.x;  // = n*256 + k
  int n = idx >> 8;
  int kk = idx & 255;
  WqT[idx] = (short)f2bf(Wq[kk * NE + n] * 0.0625f);
  WkT[idx] = (short)f2bf(Wk[kk * NE + n]);
  WoT[idx] = (short)f2bf(Wo[kk * NE + n]);
}

// acc[et][ct] += outT tile:
//   outT[e = h*128 + et*16 + c4*4+r][col = sb*32 + ct*16 + cl]
//     = sum_c WT[e][c] * inp[col][c]
// A = WT rows (global bf16, L2-hot), B = inp rows (global f32 -> bf16).
__device__ __forceinline__ void gemm_halfT(const short* __restrict__ WT,
                                           const float* __restrict__ inp,
                                           int h, int sb, int cl, int c4,
                                           f32x4 acc[8][2]) {
  #pragma unroll
  for (int ks = 0; ks < 8; ++ks) {
    bf16x8 bb[2];
    #pragma unroll
    for (int ct = 0; ct < 2; ++ct) {
      const float* rp = inp + (sb * 32 + ct * 16 + cl) * NE + ks * 32 + c4 * 8;
      bb[ct] = cvt8(*reinterpret_cast<const float4*>(rp),
                    *reinterpret_cast<const float4*>(rp + 4));
    }
    #pragma unroll
    for (int eh = 0; eh < 2; ++eh) {
      bf16x8 a[4];
      #pragma unroll
      for (int e4 = 0; e4 < 4; ++e4) {
        int et = eh * 4 + e4;
        a[e4] = *reinterpret_cast<const bf16x8*>(
            WT + (h * 128 + et * 16 + cl) * NE + ks * 32 + c4 * 8);
      }
      #pragma unroll
      for (int e4 = 0; e4 < 4; ++e4)
        #pragma unroll
        for (int ct = 0; ct < 2; ++ct)
          acc[eh * 4 + e4][ct] = MF(a[e4], bb[ct], acc[eh * 4 + e4][ct]);
    }
  }
}

__global__ __launch_bounds__(512, 2)
void fused_attn3(const float* __restrict__ q,
                 const float* __restrict__ kin,
                 const int* __restrict__ am,
                 const short* __restrict__ WqT,
                 const short* __restrict__ WkT,
                 const short* __restrict__ WoT,
                 const float* __restrict__ bq,
                 const float* __restrict__ bk,
                 const float* __restrict__ bo,
                 float* __restrict__ out) {
  // 64KB, time-shared: KT[e][m] (256 rows x 256B, swizzled) until GEMM2 done,
  // then P[s][j] (128 rows x 512B, swizzled) for GEMM3.
  __shared__ char LB[65536];
  const int t = threadIdx.x;
  const int lane = t & 63;
  const int wid = t >> 6;        // 8 waves
  const int cl = lane & 15;
  const int c4 = lane >> 4;
  const int h = wid >> 2;        // head / e-half (0..1)
  const int sb = wid & 3;        // s-band & m-band (0..3, 32 wide)
  const int b = blockIdx.x;
  const float* qb = q + (size_t)b * (NS * NE);
  const float* kb = kin + (size_t)b * (NS * NE);

  // ---- GEMM1a: KT = (k @ Wk + bk)^T  (e-half h rows, m-band sb cols) ----
  {
    f32x4 acc[8][2];
    #pragma unroll
    for (int et = 0; et < 8; ++et)
      #pragma unroll
      for (int ct = 0; ct < 2; ++ct) acc[et][ct] = (f32x4){0.f, 0.f, 0.f, 0.f};
    gemm_halfT(WkT, kb, h, sb, cl, c4, acc);
    #pragma unroll
    for (int et = 0; et < 8; ++et) {
      int e0 = h * 128 + et * 16 + c4 * 4;       // 4 consecutive e (rows)
      float4 bk4 = *reinterpret_cast<const float4*>(bk + e0);
      #pragma unroll
      for (int mt = 0; mt < 2; ++mt) {
        int m = sb * 32 + mt * 16 + cl;
        #pragma unroll
        for (int r = 0; r < 4; ++r) {
          int e = e0 + r;
          float bv = (r == 0) ? bk4.x : (r == 1) ? bk4.y : (r == 2) ? bk4.z : bk4.w;
          *reinterpret_cast<unsigned short*>(
              LB + e * 256 + ((m * 2) ^ ((e & 7) << 4))) =
              f2bf(acc[et][mt][r] + bv);
        }
      }
    }
  }

  // ---- GEMM1b: qpT in registers (e-half h, s-band sb), packed to bf16 ----
  // qpk[et][st][p]: qpT rows (in tile et) c4*4 + {2p,2p+1}, col = st*16+cl.
  unsigned qpk[8][2][2];
  {
    f32x4 acc[8][2];
    #pragma unroll
    for (int et = 0; et < 8; ++et)
      #pragma unroll
      for (int ct = 0; ct < 2; ++ct) acc[et][ct] = (f32x4){0.f, 0.f, 0.f, 0.f};
    gemm_halfT(WqT, qb, h, sb, cl, c4, acc);   // WqT prescaled by 1/16
    #pragma unroll
    for (int et = 0; et < 8; ++et) {
      int e0 = h * 128 + et * 16 + c4 * 4;
      float4 bq4 = *reinterpret_cast<const float4*>(bq + e0);
      #pragma unroll
      for (int st = 0; st < 2; ++st) {
        qpk[et][st][0] = packbf(acc[et][st][0] + bq4.x * 0.0625f,
                                acc[et][st][1] + bq4.y * 0.0625f);
        qpk[et][st][1] = packbf(acc[et][st][2] + bq4.z * 0.0625f,
                                acc[et][st][3] + bq4.w * 0.0625f);
      }
    }
  }
  __syncthreads();   // KT fully written (all waves) before score reads

  // ---- GEMM2 (split over st to halve live regs):
  // scoresT[j][s] = sum_m KT[h*128+j][m] * qpT[h*128+m][s], K=16 chain on the
  // K=32 MFMA (k-slots {c4*8..+3} carry m = ks*16+c4*4+{0..3}; upper 4 zeroed).
  unsigned prpk[2][8][2];   // packed probs, [st][jt][pair]
  #pragma unroll
  for (int st = 0; st < 2; ++st) {
    f32x4 sacc[8];
    #pragma unroll
    for (int jt = 0; jt < 8; ++jt) sacc[jt] = (f32x4){0.f, 0.f, 0.f, 0.f};
    #pragma unroll
    for (int ks = 0; ks < 8; ++ks) {
      BF8 bb;
      bb.u[0] = qpk[ks][st][0]; bb.u[1] = qpk[ks][st][1];
      bb.u[2] = 0; bb.u[3] = 0;
      #pragma unroll
      for (int jh = 0; jh < 2; ++jh) {
        BF8 a[4];
        #pragma unroll
        for (int j4 = 0; j4 < 4; ++j4) {
          int jt = jh * 4 + j4;
          uint2 d = *reinterpret_cast<const uint2*>(
              LB + (h * 128 + jt * 16 + cl) * 256 +
              ((ks * 32 + c4 * 8) ^ ((cl & 7) << 4)));
          a[j4].u[0] = d.x; a[j4].u[1] = d.y; a[j4].u[2] = 0; a[j4].u[3] = 0;
        }
        #pragma unroll
        for (int j4 = 0; j4 < 4; ++j4)
          sacc[jh * 4 + j4] = MF(a[j4].v, bb.v, sacc[jh * 4 + j4]);
      }
    }
    // fold additive mask: +1.0 where attention_mask[b][j]==0  (j-axis!)
    #pragma unroll
    for (int jt = 0; jt < 8; ++jt) {
      int4 mv = *reinterpret_cast<const int4*>(am + b * NS + jt * 16 + c4 * 4);
      sacc[jt][0] += (mv.x == 0) ? 1.f : 0.f;
      sacc[jt][1] += (mv.y == 0) ? 1.f : 0.f;
      sacc[jt][2] += (mv.z == 0) ? 1.f : 0.f;
      sacc[jt][3] += (mv.w == 0) ? 1.f : 0.f;
    }
    // softmax along j: 32 in-lane values, then xor 16/32 across c4 groups
    float mx = -1e30f;
    #pragma unroll
    for (int jt = 0; jt < 8; ++jt)
      #pragma unroll
      for (int r = 0; r < 4; ++r) mx = fmaxf(mx, sacc[jt][r]);
    mx = fmaxf(mx, __shfl_xor(mx, 16, 64));
    mx = fmaxf(mx, __shfl_xor(mx, 32, 64));
    float sum = 0.f;
    #pragma unroll
    for (int jt = 0; jt < 8; ++jt)
      #pragma unroll
      for (int r = 0; r < 4; ++r) {
        float ev = __expf(sacc[jt][r] - mx);
        sacc[jt][r] = ev;
        sum += ev;
      }
    sum += __shfl_xor(sum, 16, 64);
    sum += __shfl_xor(sum, 32, 64);
    float rinv = 1.0f / sum;
    #pragma unroll
    for (int jt = 0; jt < 8; ++jt) {
      prpk[st][jt][0] = packbf(sacc[jt][0] * rinv, sacc[jt][1] * rinv);
      prpk[st][jt][1] = packbf(sacc[jt][2] * rinv, sacc[jt][3] * rinv);
    }
  }
  __syncthreads();   // all KT reads complete before P overwrites the region

  // ---- P[s][j] = probs bf16 (128 rows x 512B, swizzled) ----
  #pragma unroll
  for (int st = 0; st < 2; ++st) {
    int s = sb * 32 + st * 16 + cl;
    #pragma unroll
    for (int jt = 0; jt < 8; ++jt) {
      int j = h * 128 + jt * 16 + c4 * 4;
      *reinterpret_cast<uint2*>(
          LB + s * 512 + ((j * 2) ^ ((s & 7) << 4))) =
          make_uint2(prpk[st][jt][0], prpk[st][jt][1]);
    }
  }
  __syncthreads();

  // ---- GEMM3 (transposed): out[s][e] = sum_j Wo[j][e] * P[s][j] + bo[e]
  // A = WoT rows e (global, L2-hot), B = P rows s (LDS).  D rows = e -> the
  // 4 acc elems are 4 consecutive e => float4 stores.
  float* ob = out + (size_t)b * (NS * NE);
  #pragma unroll
  for (int eti = 0; eti < 2; ++eti) {
    const int et = wid * 2 + eti;               // 16 e-tiles over 8 waves
    bf16x8 a[8];
    #pragma unroll
    for (int ks = 0; ks < 8; ++ks)
      a[ks] = *reinterpret_cast<const bf16x8*>(
          WoT + (et * 16 + cl) * NE + ks * 32 + c4 * 8);
    float4 bo4 = *reinterpret_cast<const float4*>(bo + et * 16 + c4 * 4);
    #pragma unroll
    for (int su = 0; su < 8; ++su) {
      f32x4 acc = (f32x4){0.f, 0.f, 0.f, 0.f};
      const int row = su * 16 + cl;
      #pragma unroll
      for (int ks = 0; ks < 8; ++ks) {
        bf16x8 bv = *reinterpret_cast<const bf16x8*>(
            LB + row * 512 + ((ks * 64 + c4 * 16) ^ ((row & 7) << 4)));
        acc = MF(a[ks], bv, acc);
      }
      float4 o;
      o.x = acc[0] + bo4.x;
      o.y = acc[1] + bo4.y;
      o.z = acc[2] + bo4.z;
      o.w = acc[3] + bo4.w;
      *reinterpret_cast<float4*>(ob + row * NE + et * 16 + c4 * 4) = o;
    }
  }
}

extern "C" void kernel_launch(void* const* d_in, const int* in_sizes, int n_in,
                              void* d_out, int out_size, void* d_ws, size_t ws_size,
                              hipStream_t stream) {
  const float* q  = (const float*)d_in[0];
  const float* k  = (const float*)d_in[1];
  // d_in[2] = v : dead in the reference, never touched
  const int*   am = (const int*)d_in[3];
  const float* Wq = (const float*)d_in[4];
  const float* bq = (const float*)d_in[5];
  const float* Wk = (const float*)d_in[6];
  const float* bk = (const float*)d_in[7];
  // d_in[8] = Wv, d_in[9] = bv : dead
  const float* Wo = (const float*)d_in[10];
  const float* bo = (const float*)d_in[11];
  float* out = (float*)d_out;

  // workspace: 3 x 256x256 bf16 transposed weights = 384KB
  short* WqT = (short*)d_ws;
  short* WkT = WqT + NE * NE;
  short* WoT = WkT + NE * NE;

  prep_weights<<<NE * NE / 256, 256, 0, stream>>>(Wq, Wk, Wo, WqT, WkT, WoT);
  fused_attn3<<<NB, 512, 0, stream>>>(q, k, am, WqT, WkT, WoT, bq, bk, bo, out);
}